// Round 3
// baseline (537.984 us; speedup 1.0000x reference)
//
#include <hip/hip_runtime.h>
#include <hip/hip_fp16.h>

// Problem: B=4, S=2048, H=8, E=64. BH=32 heads total.
// R11: mask generation BALANCED across attn's two passes (R10 measured the
//      threefry VALU floor at ~250us busy-equivalent at 91% VALUBusy — issue
//      bound, not fixable; R8 proved inline overlap works but packed all mask
//      into pass B at 79% busy). Split per kt: pass A computes hashes j_=0..3
//      (bits 0-3,8-11) and stores the partial u16 to Mw (thread-owned slot,
//      R10-verified layout/consumption path); pass B computes j_=4..7 inline
//      and ORs with the prefetched partial. Every hash bit-identical to R8/R10.
//      Q/K projections merged into one launch (pointer select on blockIdx).
//      Mask still aliases d_out (block's 64KB mask region == its out region;
//      reads precede the epilogue writes; all same-block).
// Workspace: Qh 0, Ql 8M, Kh 16M, Kl 24M, Vth 32M, Vtl 40M  (48 MiB)

typedef _Float16 f16;
typedef _Float16 f16x4 __attribute__((ext_vector_type(4)));
typedef _Float16 f16x8 __attribute__((ext_vector_type(8)));
typedef float f32x4v __attribute__((ext_vector_type(4)));
typedef unsigned int u32;
typedef unsigned short u16;

// ---------------- threefry2x32 (jax partitionable), key (0,42) — macro-inlined ----------------
// per flat i over [B,H,S,S]: (b1,b2)=threefry2x32((0,42),(0,i)); keep <=> (b1^b2) < 0xE6666600
#define QR2(r) \
    a0 += a1; b0 += b1; \
    a1 = __builtin_rotateleft32(a1, r); b1 = __builtin_rotateleft32(b1, r); \
    a1 ^= a0; b1 ^= b0;
#define TF4(p,q,rr,s) QR2(p) QR2(q) QR2(rr) QR2(s)
#define TF_FULL \
    TF4(13,15,26,6)   a0 += 42u;          a1 += 0x1BD11BF1u;  b0 += 42u;          b1 += 0x1BD11BF1u; \
    TF4(17,29,16,24)  a0 += 0x1BD11BF0u;  a1 += 2u;           b0 += 0x1BD11BF0u;  b1 += 2u; \
    TF4(13,15,26,6)                       a1 += 45u;                              b1 += 45u; \
    TF4(17,29,16,24)  a0 += 42u;          a1 += 0x1BD11BF4u;  b0 += 42u;          b1 += 0x1BD11BF4u; \
    TF4(13,15,26,6)   a0 += 0x1BD11BF0u;  a1 += 5u;           b0 += 0x1BD11BF0u;  b1 += 5u;

// Half of the 16 mask bits for one (attn-thread, kt) unit: hashes j_ = J0..J0+3.
// rows qt*256 + w*16 + kg*4 + r (r=0..3), cols kt*64 + n*16 + lrow (n=0..3),
// bit index n*4 + r. Chain a: bit j_ (n = j_>>2? -> n∈{0,1}); chain b: bit j_+8 (+32 cols).
#define MASK8(ktArg, J0, dst) do { \
    u32 wm_ = 0u; \
    const u32 cb_ = ((u32)(bh * 2048 + qt * 256 + w * 16 + kg * 4) << 11) \
                  + (u32)(ktArg) * 64u + (u32)lrow + 42u; \
    _Pragma("unroll") \
    for (int j_ = J0; j_ < J0 + 4; ++j_) { \
        u32 a0 = 0u, a1 = cb_ + (u32)((j_ >> 2) * 16 + (j_ & 3) * 2048); \
        u32 b0 = 0u, b1 = a1 + 32u; \
        TF_FULL \
        wm_ |= ((a0 ^ a1) < 0xE6666600u) ? (1u << j_) : 0u; \
        wm_ |= ((b0 ^ b1) < 0xE6666600u) ? (1u << (j_ + 8)) : 0u; \
    } \
    (dst) = wm_; \
} while (0)

// ---------------- fused Q+K proj: out[f] = sum_e x[e]*W[f][e] + b[f], [b,h,s,e] ----------------
// blocks 0..511 -> Q, 512..1023 -> K (identical code path, pointer select)
__global__ __launch_bounds__(256) void proj_qk_kernel(
    const float* __restrict__ Xq, const float* __restrict__ Xk,
    const float* __restrict__ Wq, const float* __restrict__ Wk,
    const float* __restrict__ bq, const float* __restrict__ bk,
    f16* __restrict__ Qh, f16* __restrict__ Ql,
    f16* __restrict__ Kh, f16* __restrict__ Kl)
{
    __shared__ __align__(16) float Wl[64 * 68];
    __shared__ __align__(16) float Xl[128 * 68];
    const int t = threadIdx.x;
    const int isK = (int)(blockIdx.x >> 9);
    const float* X    = isK ? Xk : Xq;
    const float* W    = isK ? Wk : Wq;
    const float* bias = isK ? bk : bq;
    f16* Oh = isK ? Kh : Qh;
    f16* Ol = isK ? Kl : Ql;
    const int tb = (int)(blockIdx.x & 511) * 128;

    for (int c = t; c < 1024; c += 256) {
        int f = c >> 4, e4 = (c & 15) << 2;
        *(float4*)&Wl[f * 68 + e4] = *(const float4*)(W + f * 64 + e4);
    }
    for (int c = t; c < 2048; c += 256) {
        int tok = c >> 4, e4 = (c & 15) << 2;
        *(float4*)&Xl[tok * 68 + e4] = *(const float4*)(X + (size_t)(tb + tok) * 64 + e4);
    }
    __syncthreads();

    const int tx = t & 15;
    const int ty = t >> 4;
    const int f0 = ty * 4;

    float acc[8][4];
#pragma unroll
    for (int i = 0; i < 8; ++i)
#pragma unroll
        for (int j = 0; j < 4; ++j) acc[i][j] = bias[f0 + j];

    for (int e = 0; e < 64; e += 4) {
        float4 wv[4];
#pragma unroll
        for (int j = 0; j < 4; ++j) wv[j] = *(float4*)&Wl[(f0 + j) * 68 + e];
#pragma unroll
        for (int i = 0; i < 8; ++i) {
            float4 xv = *(float4*)&Xl[(tx + 16 * i) * 68 + e];
#pragma unroll
            for (int j = 0; j < 4; ++j)
                acc[i][j] += xv.x * wv[j].x + xv.y * wv[j].y + xv.z * wv[j].z + xv.w * wv[j].w;
        }
    }

#pragma unroll
    for (int i = 0; i < 8; ++i) {
        int tin = tb + tx + 16 * i;
        int h  = tin & 7;
        int bs = tin >> 3;
        int b  = bs >> 11;
        int s  = bs & 2047;
        size_t o = ((size_t)(b * 8 + h) * 2048 + s) * 64 + f0;
        f16x4 hv, lv;
#pragma unroll
        for (int j = 0; j < 4; ++j) {
            float a = acc[i][j];
            f16 hh = (f16)a;
            hv[j] = hh;
            lv[j] = (f16)(a - (float)hh);
        }
        *(f16x4*)(Oh + o) = hv;
        *(f16x4*)(Ol + o) = lv;
    }
}

// ---------------- proj_v: one (bh, 128-s chunk) per block; store [b,h,e,s] coalesced ----------------
__global__ __launch_bounds__(256) void proj_v_kernel(
    const float* __restrict__ X, const float* __restrict__ W,
    const float* __restrict__ bias,
    f16* __restrict__ Oh, f16* __restrict__ Ol)
{
    __shared__ __align__(16) float Wl[64 * 68];
    __shared__ __align__(16) float Xl[128 * 68];   // reused as Th/Tl after compute
    const int t = threadIdx.x;
    const int sc0 = blockIdx.x * 128;
    const int bh = blockIdx.y, b = bh >> 3, h = bh & 7;

    for (int c = t; c < 1024; c += 256) {
        int f = c >> 4, e4 = (c & 15) << 2;
        *(float4*)&Wl[f * 68 + e4] = *(const float4*)(W + f * 64 + e4);
    }
    for (int c = t; c < 2048; c += 256) {          // tokens of same (b,h): stride 8 in [B,S,H,E]
        int tok = c >> 4, e4 = (c & 15) << 2;
        size_t src = ((size_t)(b * 2048 + sc0 + tok) * 8 + h) * 64 + e4;
        *(float4*)&Xl[tok * 68 + e4] = *(const float4*)(X + src);
    }
    __syncthreads();

    const int tx = t & 15;
    const int ty = t >> 4;
    const int f0 = ty * 4;

    float acc[8][4];
#pragma unroll
    for (int i = 0; i < 8; ++i)
#pragma unroll
        for (int j = 0; j < 4; ++j) acc[i][j] = bias[f0 + j];

    for (int e = 0; e < 64; e += 4) {
        float4 wv[4];
#pragma unroll
        for (int j = 0; j < 4; ++j) wv[j] = *(float4*)&Wl[(f0 + j) * 68 + e];
#pragma unroll
        for (int i = 0; i < 8; ++i) {
            float4 xv = *(float4*)&Xl[(tx + 16 * i) * 68 + e];
#pragma unroll
            for (int j = 0; j < 4; ++j)
                acc[i][j] += xv.x * wv[j].x + xv.y * wv[j].y + xv.z * wv[j].z + xv.w * wv[j].w;
        }
    }
    __syncthreads();                               // done reading Xl -> reuse as transpose tile

    f16* Th = (f16*)Xl;            // [64 f][136 s]
    f16* Tl = Th + 64 * 136;
#pragma unroll
    for (int i = 0; i < 8; ++i) {
        int s = tx + 16 * i;
#pragma unroll
        for (int j = 0; j < 4; ++j) {
            float a = acc[i][j];
            f16 hh = (f16)a;
            Th[(f0 + j) * 136 + s] = hh;
            Tl[(f0 + j) * 136 + s] = (f16)(a - (float)hh);
        }
    }
    __syncthreads();

    for (int c = t; c < 1024; c += 256) {          // 64 e-rows x 128 s, uint4 = 8 f16
        int e = c >> 4, sc = (c & 15) << 3;
        size_t o = ((size_t)bh * 64 + e) * 2048 + sc0 + sc;
        *(uint4*)(Oh + o) = *(uint4*)&Th[e * 136 + sc];
        *(uint4*)(Ol + o) = *(uint4*)&Tl[e * 136 + sc];
    }
}

// identical score computation for both passes (bit-identical chain order per element)
#define COMPUTE_S(S, khp, klp) do { \
    _Pragma("unroll") for (int n = 0; n < 4; ++n) S[n] = f32x4v{0.f,0.f,0.f,0.f}; \
    _Pragma("unroll") for (int n = 0; n < 4; ++n) { \
        _Pragma("unroll") for (int ks = 0; ks < 2; ++ks) { \
            const int off_ = (n * 16 + lrow) * LDK + ks * 32 + kg * 8; \
            f16x8 bhf_ = *(const f16x8*)&(khp)[off_]; \
            f16x8 blf_ = *(const f16x8*)&(klp)[off_]; \
            S[n] = __builtin_amdgcn_mfma_f32_16x16x32_f16(qh[ks], bhf_, S[n], 0, 0, 0); \
            S[n] = __builtin_amdgcn_mfma_f32_16x16x32_f16(ql[ks], bhf_, S[n], 0, 0, 0); \
            S[n] = __builtin_amdgcn_mfma_f32_16x16x32_f16(qh[ks], blf_, S[n], 0, 0, 0); \
        } \
    } } while (0)

// grid (8, 32): x = 256-row Q tile, y = bh. 16 waves x 16 rows. 1 block/CU.
// MFMA 16x16x32 f16. A: A[m=lane&15][k=(lane>>4)*8+j]; B: B[k][n=lane&15];
// C: row=(lane>>4)*4+r, col=lane&15.
__global__ __launch_bounds__(1024, 4) void attn_kernel(
    const f16* __restrict__ Qh, const f16* __restrict__ Ql,
    const f16* __restrict__ Kh, const f16* __restrict__ Kl,
    const f16* __restrict__ Vth, const f16* __restrict__ Vtl,
    u16* Mw, float* out)                // Mw aliases out: deliberately NOT restrict
{
    constexpr int LDK = 88;   // f16 stride: 176 B rows (16B aligned)
    __shared__ __align__(16) f16 kh_l[2][64 * LDK];   // double-buffered
    __shared__ __align__(16) f16 kl_l[2][64 * LDK];
    __shared__ __align__(16) f16 vh_l[2][64 * LDK];   // [e][s]
    __shared__ __align__(16) f16 vl_l[2][64 * LDK];
    __shared__ __align__(16) f16 p_l[16][16 * LDK];   // per-wave P tile (16 rows)

    const int t = threadIdx.x;
    const int w = t >> 6;
    const int lane = t & 63;
    const int lrow = lane & 15;
    const int kg = lane >> 4;
    const int qt = blockIdx.x;
    const int bh = blockIdx.y;

    // staging role: threads 0..511 -> K, 512..1023 -> V. One uint4 pair each.
    const int sc  = t & 511;
    const int sx  = sc >> 3;            // K row / V e-row
    const int sc8 = (sc & 7) << 3;
    const bool isK = (t < 512);

    // persistent Q fragments (hi/lo), one 16-row m-tile per wave, 2 k-steps
    f16x8 qh[2], ql[2];
    {
        size_t rowg = (size_t)bh * 2048 + qt * 256 + w * 16 + lrow;
        const f16* ph = Qh + rowg * 64 + kg * 8;
        const f16* pl = Ql + rowg * 64 + kg * 8;
        qh[0] = *(const f16x8*)(ph);
        qh[1] = *(const f16x8*)(ph + 32);
        ql[0] = *(const f16x8*)(pl);
        ql[1] = *(const f16x8*)(pl + 32);
    }

    const size_t kbase = (size_t)bh * 2048 * 64;   // same footprint for K and Vt
    u16* mrow = Mw + (size_t)(bh * 8 + qt) * 32768 + t;   // this thread's mask slots

    // ---- pass A: row sums l = sum exp(s - 8); K only, double-buffered.
    //      Also: generate mask HALF (hashes j_=0..3) per kt, store partial u16. ----
    float lsum[4] = {0.f, 0.f, 0.f, 0.f};
    if (isK) {      // prologue: stage kt=0 into buf 0
        size_t g = kbase + (size_t)(sx * 64) + sc8;
        uint4 h4 = *(const uint4*)(Kh + g);
        uint4 l4 = *(const uint4*)(Kl + g);
        *(uint4*)&kh_l[0][sx * LDK + sc8] = h4;
        *(uint4*)&kl_l[0][sx * LDK + sc8] = l4;
    }
    __syncthreads();

    for (int kt = 0; kt < 32; ++kt) {
        const int cur = kt & 1;
        uint4 sA, sB;
        if (isK && kt < 31) {           // issue next tile's loads early
            size_t g = kbase + (size_t)((kt + 1) * 64 + sx) * 64 + sc8;
            sA = *(const uint4*)(Kh + g);
            sB = *(const uint4*)(Kl + g);
        }

        u32 mpart;
        MASK8(kt, 0, mpart);            // half the threefry work, hides pass-A latency

        f32x4v sfr[4];
        COMPUTE_S(sfr, kh_l[cur], kl_l[cur]);
#pragma unroll
        for (int n = 0; n < 4; ++n)
#pragma unroll
            for (int r = 0; r < 4; ++r)
                lsum[r] += __expf(fmaf(sfr[n][r], 0.125f, -8.0f));

        mrow[(size_t)kt * 1024] = (u16)mpart;   // own slot; re-read in pass B

        if (isK && kt < 31) {           // commit after compute
            *(uint4*)&kh_l[cur ^ 1][sx * LDK + sc8] = sA;
            *(uint4*)&kl_l[cur ^ 1][sx * LDK + sc8] = sB;
        }
        __syncthreads();                // single barrier per kt
    }

    float rsc[4];
#pragma unroll
    for (int r = 0; r < 4; ++r) {
        float v = lsum[r];
        v += __shfl_xor(v, 1);
        v += __shfl_xor(v, 2);
        v += __shfl_xor(v, 4);
        v += __shfl_xor(v, 8);
        rsc[r] = 1.0f / (0.9f * v);   // folds dropout 1/(1-p)
    }

    // ---- pass B: recompute s, exact p, mask = stored half | inline half, fp16 cast, PV ----
    f32x4v oacc[4];
#pragma unroll
    for (int fn = 0; fn < 4; ++fn) oacc[fn] = f32x4v{0.f, 0.f, 0.f, 0.f};

    // partial-mask stream for this thread: one u16 per kt, prefetch distance 2
    u32 m0 = mrow[0];
    u32 m1 = mrow[1024];

    {   // prologue: stage kt=0 (K and V) into buf 0
        if (isK) {
            size_t g = kbase + (size_t)(sx * 64) + sc8;
            uint4 h4 = *(const uint4*)(Kh + g);
            uint4 l4 = *(const uint4*)(Kl + g);
            *(uint4*)&kh_l[0][sx * LDK + sc8] = h4;
            *(uint4*)&kl_l[0][sx * LDK + sc8] = l4;
        } else {
            size_t g = kbase + (size_t)sx * 2048 + sc8;
            uint4 h4 = *(const uint4*)(Vth + g);
            uint4 l4 = *(const uint4*)(Vtl + g);
            *(uint4*)&vh_l[0][sx * LDK + sc8] = h4;
            *(uint4*)&vl_l[0][sx * LDK + sc8] = l4;
        }
    }
    __syncthreads();

    for (int kt = 0; kt < 32; ++kt) {
        const int cur = kt & 1;
        uint4 sA, sB;
        if (kt < 31) {                  // issue next tile's loads early
            if (isK) {
                size_t g = kbase + (size_t)((kt + 1) * 64 + sx) * 64 + sc8;
                sA = *(const uint4*)(Kh + g);
                sB = *(const uint4*)(Kl + g);
            } else {
                size_t g = kbase + (size_t)sx * 2048 + (kt + 1) * 64 + sc8;
                sA = *(const uint4*)(Vth + g);
                sB = *(const uint4*)(Vtl + g);
            }
        }
        u32 mn = 0u;
        if (kt < 30) mn = mrow[(size_t)(kt + 2) * 1024];   // partial-mask prefetch

        u32 mB;
        MASK8(kt, 4, mB);               // other half of the threefry work
        const u32 pm = m0 | mB;         // full 16 dropout bits for this kt

        f32x4v sfr[4];
        COMPUTE_S(sfr, kh_l[cur], kl_l[cur]);

#pragma unroll
        for (int n = 0; n < 4; ++n)
#pragma unroll
            for (int r = 0; r < 4; ++r) {
                float e = __expf(fmaf(sfr[n][r], 0.125f, -8.0f));
                float p = e * rsc[r];
                if (!((pm >> (n * 4 + r)) & 1u)) p = 0.0f;
                p_l[w][(kg * 4 + r) * LDK + n * 16 + lrow] = (f16)p;  // RTNE = astype(f16)
            }

        // PV: out += P(16f exact) * (Vh + Vl)   (wave-private p_l: no barrier)
#pragma unroll
        for (int ks = 0; ks < 2; ++ks) {
            f16x8 pa0 = *(const f16x8*)&p_l[w][lrow * LDK + ks * 32 + kg * 8];
#pragma unroll
            for (int fn = 0; fn < 4; ++fn) {
                const int voff = (fn * 16 + lrow) * LDK + ks * 32 + kg * 8;
                f16x8 vhf = *(const f16x8*)&vh_l[cur][voff];
                f16x8 vlf = *(const f16x8*)&vl_l[cur][voff];
                oacc[fn] = __builtin_amdgcn_mfma_f32_16x16x32_f16(pa0, vhf, oacc[fn], 0, 0, 0);
                oacc[fn] = __builtin_amdgcn_mfma_f32_16x16x32_f16(pa0, vlf, oacc[fn], 0, 0, 0);
            }
        }

        if (kt < 31) {                  // commit after compute
            if (isK) {
                *(uint4*)&kh_l[cur ^ 1][sx * LDK + sc8] = sA;
                *(uint4*)&kl_l[cur ^ 1][sx * LDK + sc8] = sB;
            } else {
                *(uint4*)&vh_l[cur ^ 1][sx * LDK + sc8] = sA;
                *(uint4*)&vl_l[cur ^ 1][sx * LDK + sc8] = sB;
            }
        }
        m0 = m1; m1 = mn;               // rotate mask prefetch registers
        __syncthreads();                // single barrier per kt
    }

    // epilogue: out [b,h,s,e] fp32  (overwrites this block's own mask region)
#pragma unroll
    for (int fn = 0; fn < 4; ++fn)
#pragma unroll
        for (int r = 0; r < 4; ++r) {
            int row = qt * 256 + w * 16 + kg * 4 + r;
            out[((size_t)bh * 2048 + row) * 64 + fn * 16 + lrow] = oacc[fn][r];
        }
}

extern "C" void kernel_launch(void* const* d_in, const int* in_sizes, int n_in,
                              void* d_out, int out_size, void* d_ws, size_t ws_size,
                              hipStream_t stream) {
    (void)in_sizes; (void)n_in; (void)out_size; (void)ws_size;
    const float* query = (const float*)d_in[0];
    const float* key_  = (const float*)d_in[1];
    const float* value = (const float*)d_in[2];
    const float* Wq = (const float*)d_in[3];
    const float* bq = (const float*)d_in[4];
    const float* Wk = (const float*)d_in[5];
    const float* bk = (const float*)d_in[6];
    const float* Wv = (const float*)d_in[7];
    const float* bv = (const float*)d_in[8];

    char* ws = (char*)d_ws;                 // needs 48 MiB
    f16* Qh  = (f16*)(ws);
    f16* Ql  = (f16*)(ws + 8388608);
    f16* Kh  = (f16*)(ws + 16777216);
    f16* Kl  = (f16*)(ws + 25165824);
    f16* Vth = (f16*)(ws + 33554432);
    f16* Vtl = (f16*)(ws + 41943040);

    u16* Mw = (u16*)d_out;                  // mask partials alias the output buffer

    proj_qk_kernel<<<1024, 256, 0, stream>>>(query, key_, Wq, Wk, bq, bk, Qh, Ql, Kh, Kl);
    proj_v_kernel<<<dim3(16, 32), 256, 0, stream>>>(value, Wv, bv, Vth, Vtl);
    attn_kernel<<<dim3(8, 32), 1024, 0, stream>>>(Qh, Ql, Kh, Kl, Vth, Vtl, Mw, (float*)d_out);
}

// Round 4
// 472.603 us; speedup vs baseline: 1.1383x; 1.1383x over previous
//
#include <hip/hip_runtime.h>
#include <hip/hip_fp16.h>

// Problem: B=4, S=2048, H=8, E=64. BH=32 heads total.
// R12: revert to R8 structure (mask fully fused in attn pass B — best measured
//      packing: R8 attn=397us vs R11 split=476us vs R10 serial=453us). Change:
//      MASK16 rewritten with 4 interleaved threefry chains (2 j_ per TF pass,
//      bit-identical hashes) + rotates forced to v_alignbit_b32. R10 showed the
//      standalone mask runs at only ~45% of the VALU issue floor (277us vs
//      ~125us theoretical) with the compiler serializing 2-way-ILP chains at
//      minimal VGPR — the chain is dependent-latency-bound. 4-way ILP halves
//      latency exposure. Q+K proj merged into one launch (R11, verified).
// Workspace: Qh 0, Ql 8M, Kh 16M, Kl 24M, Vth 32M, Vtl 40M  (48 MiB)

typedef _Float16 f16;
typedef _Float16 f16x4 __attribute__((ext_vector_type(4)));
typedef _Float16 f16x8 __attribute__((ext_vector_type(8)));
typedef float f32x4v __attribute__((ext_vector_type(4)));
typedef unsigned int u32;
typedef unsigned short u16;

// ---------------- threefry2x32 (jax partitionable), key (0,42) ----------------
// per flat i over [B,H,S,S]: (b1,b2)=threefry2x32((0,42),(0,i)); keep <=> (b1^b2) < 0xE6666600
// 4 chains (a,b,c,d) interleaved for ILP; per-chain math bit-identical to the
// verified 2-chain version.
#define ROTL(x, r) __builtin_amdgcn_alignbit((x), (x), 32 - (r))
#define QR4(r) \
    a0 += a1; b0 += b1; c0 += c1; d0 += d1; \
    a1 = ROTL(a1, r); b1 = ROTL(b1, r); c1 = ROTL(c1, r); d1 = ROTL(d1, r); \
    a1 ^= a0; b1 ^= b0; c1 ^= c0; d1 ^= d0;
#define TF4_4(p,q,rr,s) QR4(p) QR4(q) QR4(rr) QR4(s)
#define INJ4_0(k) a0 += (k); b0 += (k); c0 += (k); d0 += (k);
#define INJ4_1(k) a1 += (k); b1 += (k); c1 += (k); d1 += (k);
#define TF_FULL4 \
    TF4_4(13,15,26,6)   INJ4_0(42u)          INJ4_1(0x1BD11BF1u) \
    TF4_4(17,29,16,24)  INJ4_0(0x1BD11BF0u)  INJ4_1(2u) \
    TF4_4(13,15,26,6)                        INJ4_1(45u) \
    TF4_4(17,29,16,24)  INJ4_0(42u)          INJ4_1(0x1BD11BF4u) \
    TF4_4(13,15,26,6)   INJ4_0(0x1BD11BF0u)  INJ4_1(5u)

// 16 PRIVATE mask bits for this thread's own elements:
// rows qt*256 + w*16 + kg*4 + r (r=0..3), cols kt*64 + n*16 + lrow (n=0..3).
// bit index = n*4 + r. a-chain: bit j_; b-chain: bit j_+8 (+32 cols);
// c-chain: bit j_+1; d-chain: bit j_+9. Hashes identical to 2-chain version.
#define MASK16(ktArg, dst) do { \
    u32 wm_ = 0u; \
    const u32 cb_ = ((u32)(bh * 2048 + qt * 256 + w * 16 + kg * 4) << 11) \
                  + (u32)(ktArg) * 64u + (u32)lrow + 42u; \
    _Pragma("unroll") \
    for (int j_ = 0; j_ < 8; j_ += 2) { \
        u32 a0 = 0u, a1 = cb_ + (u32)((j_ >> 2) * 16 + (j_ & 3) * 2048); \
        u32 b0 = 0u, b1 = a1 + 32u; \
        u32 c0 = 0u, c1 = cb_ + (u32)(((j_ + 1) >> 2) * 16 + ((j_ + 1) & 3) * 2048); \
        u32 d0 = 0u, d1 = c1 + 32u; \
        TF_FULL4 \
        wm_ |= ((a0 ^ a1) < 0xE6666600u) ? (1u << j_) : 0u; \
        wm_ |= ((b0 ^ b1) < 0xE6666600u) ? (1u << (j_ + 8)) : 0u; \
        wm_ |= ((c0 ^ c1) < 0xE6666600u) ? (1u << (j_ + 1)) : 0u; \
        wm_ |= ((d0 ^ d1) < 0xE6666600u) ? (1u << (j_ + 9)) : 0u; \
    } \
    (dst) = wm_; \
} while (0)

// ---------------- fused Q+K proj: out[f] = sum_e x[e]*W[f][e] + b[f], [b,h,s,e] ----------------
// blocks 0..511 -> Q, 512..1023 -> K (identical code path, pointer select)
__global__ __launch_bounds__(256) void proj_qk_kernel(
    const float* __restrict__ Xq, const float* __restrict__ Xk,
    const float* __restrict__ Wq, const float* __restrict__ Wk,
    const float* __restrict__ bq, const float* __restrict__ bk,
    f16* __restrict__ Qh, f16* __restrict__ Ql,
    f16* __restrict__ Kh, f16* __restrict__ Kl)
{
    __shared__ __align__(16) float Wl[64 * 68];
    __shared__ __align__(16) float Xl[128 * 68];
    const int t = threadIdx.x;
    const int isK = (int)(blockIdx.x >> 9);
    const float* X    = isK ? Xk : Xq;
    const float* W    = isK ? Wk : Wq;
    const float* bias = isK ? bk : bq;
    f16* Oh = isK ? Kh : Qh;
    f16* Ol = isK ? Kl : Ql;
    const int tb = (int)(blockIdx.x & 511) * 128;

    for (int c = t; c < 1024; c += 256) {
        int f = c >> 4, e4 = (c & 15) << 2;
        *(float4*)&Wl[f * 68 + e4] = *(const float4*)(W + f * 64 + e4);
    }
    for (int c = t; c < 2048; c += 256) {
        int tok = c >> 4, e4 = (c & 15) << 2;
        *(float4*)&Xl[tok * 68 + e4] = *(const float4*)(X + (size_t)(tb + tok) * 64 + e4);
    }
    __syncthreads();

    const int tx = t & 15;
    const int ty = t >> 4;
    const int f0 = ty * 4;

    float acc[8][4];
#pragma unroll
    for (int i = 0; i < 8; ++i)
#pragma unroll
        for (int j = 0; j < 4; ++j) acc[i][j] = bias[f0 + j];

    for (int e = 0; e < 64; e += 4) {
        float4 wv[4];
#pragma unroll
        for (int j = 0; j < 4; ++j) wv[j] = *(float4*)&Wl[(f0 + j) * 68 + e];
#pragma unroll
        for (int i = 0; i < 8; ++i) {
            float4 xv = *(float4*)&Xl[(tx + 16 * i) * 68 + e];
#pragma unroll
            for (int j = 0; j < 4; ++j)
                acc[i][j] += xv.x * wv[j].x + xv.y * wv[j].y + xv.z * wv[j].z + xv.w * wv[j].w;
        }
    }

#pragma unroll
    for (int i = 0; i < 8; ++i) {
        int tin = tb + tx + 16 * i;
        int h  = tin & 7;
        int bs = tin >> 3;
        int b  = bs >> 11;
        int s  = bs & 2047;
        size_t o = ((size_t)(b * 8 + h) * 2048 + s) * 64 + f0;
        f16x4 hv, lv;
#pragma unroll
        for (int j = 0; j < 4; ++j) {
            float a = acc[i][j];
            f16 hh = (f16)a;
            hv[j] = hh;
            lv[j] = (f16)(a - (float)hh);
        }
        *(f16x4*)(Oh + o) = hv;
        *(f16x4*)(Ol + o) = lv;
    }
}

// ---------------- proj_v: one (bh, 128-s chunk) per block; store [b,h,e,s] coalesced ----------------
__global__ __launch_bounds__(256) void proj_v_kernel(
    const float* __restrict__ X, const float* __restrict__ W,
    const float* __restrict__ bias,
    f16* __restrict__ Oh, f16* __restrict__ Ol)
{
    __shared__ __align__(16) float Wl[64 * 68];
    __shared__ __align__(16) float Xl[128 * 68];   // reused as Th/Tl after compute
    const int t = threadIdx.x;
    const int sc0 = blockIdx.x * 128;
    const int bh = blockIdx.y, b = bh >> 3, h = bh & 7;

    for (int c = t; c < 1024; c += 256) {
        int f = c >> 4, e4 = (c & 15) << 2;
        *(float4*)&Wl[f * 68 + e4] = *(const float4*)(W + f * 64 + e4);
    }
    for (int c = t; c < 2048; c += 256) {          // tokens of same (b,h): stride 8 in [B,S,H,E]
        int tok = c >> 4, e4 = (c & 15) << 2;
        size_t src = ((size_t)(b * 2048 + sc0 + tok) * 8 + h) * 64 + e4;
        *(float4*)&Xl[tok * 68 + e4] = *(const float4*)(X + src);
    }
    __syncthreads();

    const int tx = t & 15;
    const int ty = t >> 4;
    const int f0 = ty * 4;

    float acc[8][4];
#pragma unroll
    for (int i = 0; i < 8; ++i)
#pragma unroll
        for (int j = 0; j < 4; ++j) acc[i][j] = bias[f0 + j];

    for (int e = 0; e < 64; e += 4) {
        float4 wv[4];
#pragma unroll
        for (int j = 0; j < 4; ++j) wv[j] = *(float4*)&Wl[(f0 + j) * 68 + e];
#pragma unroll
        for (int i = 0; i < 8; ++i) {
            float4 xv = *(float4*)&Xl[(tx + 16 * i) * 68 + e];
#pragma unroll
            for (int j = 0; j < 4; ++j)
                acc[i][j] += xv.x * wv[j].x + xv.y * wv[j].y + xv.z * wv[j].z + xv.w * wv[j].w;
        }
    }
    __syncthreads();                               // done reading Xl -> reuse as transpose tile

    f16* Th = (f16*)Xl;            // [64 f][136 s]
    f16* Tl = Th + 64 * 136;
#pragma unroll
    for (int i = 0; i < 8; ++i) {
        int s = tx + 16 * i;
#pragma unroll
        for (int j = 0; j < 4; ++j) {
            float a = acc[i][j];
            f16 hh = (f16)a;
            Th[(f0 + j) * 136 + s] = hh;
            Tl[(f0 + j) * 136 + s] = (f16)(a - (float)hh);
        }
    }
    __syncthreads();

    for (int c = t; c < 1024; c += 256) {          // 64 e-rows x 128 s, uint4 = 8 f16
        int e = c >> 4, sc = (c & 15) << 3;
        size_t o = ((size_t)bh * 64 + e) * 2048 + sc0 + sc;
        *(uint4*)(Oh + o) = *(uint4*)&Th[e * 136 + sc];
        *(uint4*)(Ol + o) = *(uint4*)&Tl[e * 136 + sc];
    }
}

// identical score computation for both passes (bit-identical chain order per element)
#define COMPUTE_S(S, khp, klp) do { \
    _Pragma("unroll") for (int n = 0; n < 4; ++n) S[n] = f32x4v{0.f,0.f,0.f,0.f}; \
    _Pragma("unroll") for (int n = 0; n < 4; ++n) { \
        _Pragma("unroll") for (int ks = 0; ks < 2; ++ks) { \
            const int off_ = (n * 16 + lrow) * LDK + ks * 32 + kg * 8; \
            f16x8 bhf_ = *(const f16x8*)&(khp)[off_]; \
            f16x8 blf_ = *(const f16x8*)&(klp)[off_]; \
            S[n] = __builtin_amdgcn_mfma_f32_16x16x32_f16(qh[ks], bhf_, S[n], 0, 0, 0); \
            S[n] = __builtin_amdgcn_mfma_f32_16x16x32_f16(ql[ks], bhf_, S[n], 0, 0, 0); \
            S[n] = __builtin_amdgcn_mfma_f32_16x16x32_f16(qh[ks], blf_, S[n], 0, 0, 0); \
        } \
    } } while (0)

// grid (8, 32): x = 256-row Q tile, y = bh. 16 waves x 16 rows. 1 block/CU.
// MFMA 16x16x32 f16. A: A[m=lane&15][k=(lane>>4)*8+j]; B: B[k][n=lane&15];
// C: row=(lane>>4)*4+r, col=lane&15.
__global__ __launch_bounds__(1024, 4) void attn_kernel(
    const f16* __restrict__ Qh, const f16* __restrict__ Ql,
    const f16* __restrict__ Kh, const f16* __restrict__ Kl,
    const f16* __restrict__ Vth, const f16* __restrict__ Vtl,
    float* __restrict__ out)
{
    constexpr int LDK = 88;   // f16 stride: 176 B rows (16B aligned)
    __shared__ __align__(16) f16 kh_l[2][64 * LDK];   // double-buffered
    __shared__ __align__(16) f16 kl_l[2][64 * LDK];
    __shared__ __align__(16) f16 vh_l[2][64 * LDK];   // [e][s]
    __shared__ __align__(16) f16 vl_l[2][64 * LDK];
    __shared__ __align__(16) f16 p_l[16][16 * LDK];   // per-wave P tile (16 rows)

    const int t = threadIdx.x;
    const int w = t >> 6;
    const int lane = t & 63;
    const int lrow = lane & 15;
    const int kg = lane >> 4;
    const int qt = blockIdx.x;
    const int bh = blockIdx.y;

    // staging role: threads 0..511 -> K, 512..1023 -> V. One uint4 pair each.
    const int sc  = t & 511;
    const int sx  = sc >> 3;            // K row / V e-row
    const int sc8 = (sc & 7) << 3;
    const bool isK = (t < 512);

    // persistent Q fragments (hi/lo), one 16-row m-tile per wave, 2 k-steps
    f16x8 qh[2], ql[2];
    {
        size_t rowg = (size_t)bh * 2048 + qt * 256 + w * 16 + lrow;
        const f16* ph = Qh + rowg * 64 + kg * 8;
        const f16* pl = Ql + rowg * 64 + kg * 8;
        qh[0] = *(const f16x8*)(ph);
        qh[1] = *(const f16x8*)(ph + 32);
        ql[0] = *(const f16x8*)(pl);
        ql[1] = *(const f16x8*)(pl + 32);
    }

    const size_t kbase = (size_t)bh * 2048 * 64;   // same footprint for K and Vt

    // ---- pass A: row sums l = sum exp(s - 8); K only, double-buffered ----
    float lsum[4] = {0.f, 0.f, 0.f, 0.f};
    if (isK) {      // prologue: stage kt=0 into buf 0
        size_t g = kbase + (size_t)(sx * 64) + sc8;
        uint4 h4 = *(const uint4*)(Kh + g);
        uint4 l4 = *(const uint4*)(Kl + g);
        *(uint4*)&kh_l[0][sx * LDK + sc8] = h4;
        *(uint4*)&kl_l[0][sx * LDK + sc8] = l4;
    }
    __syncthreads();

    for (int kt = 0; kt < 32; ++kt) {
        const int cur = kt & 1;
        uint4 sA, sB;
        if (isK && kt < 31) {           // issue next tile's loads early
            size_t g = kbase + (size_t)((kt + 1) * 64 + sx) * 64 + sc8;
            sA = *(const uint4*)(Kh + g);
            sB = *(const uint4*)(Kl + g);
        }
        f32x4v sfr[4];
        COMPUTE_S(sfr, kh_l[cur], kl_l[cur]);
#pragma unroll
        for (int n = 0; n < 4; ++n)
#pragma unroll
            for (int r = 0; r < 4; ++r)
                lsum[r] += __expf(fmaf(sfr[n][r], 0.125f, -8.0f));
        if (isK && kt < 31) {           // commit after compute
            *(uint4*)&kh_l[cur ^ 1][sx * LDK + sc8] = sA;
            *(uint4*)&kl_l[cur ^ 1][sx * LDK + sc8] = sB;
        }
        __syncthreads();                // single barrier per kt
    }

    float rsc[4];
#pragma unroll
    for (int r = 0; r < 4; ++r) {
        float v = lsum[r];
        v += __shfl_xor(v, 1);
        v += __shfl_xor(v, 2);
        v += __shfl_xor(v, 4);
        v += __shfl_xor(v, 8);
        rsc[r] = 1.0f / (0.9f * v);   // folds dropout 1/(1-p)
    }

    // ---- pass B: recompute s, exact p, PRIVATE threefry dropout (4-way ILP), fp16 cast, PV ----
    f32x4v oacc[4];
#pragma unroll
    for (int fn = 0; fn < 4; ++fn) oacc[fn] = f32x4v{0.f, 0.f, 0.f, 0.f};

    {   // prologue: stage kt=0 (K and V) into buf 0
        if (isK) {
            size_t g = kbase + (size_t)(sx * 64) + sc8;
            uint4 h4 = *(const uint4*)(Kh + g);
            uint4 l4 = *(const uint4*)(Kl + g);
            *(uint4*)&kh_l[0][sx * LDK + sc8] = h4;
            *(uint4*)&kl_l[0][sx * LDK + sc8] = l4;
        } else {
            size_t g = kbase + (size_t)sx * 2048 + sc8;
            uint4 h4 = *(const uint4*)(Vth + g);
            uint4 l4 = *(const uint4*)(Vtl + g);
            *(uint4*)&vh_l[0][sx * LDK + sc8] = h4;
            *(uint4*)&vl_l[0][sx * LDK + sc8] = l4;
        }
    }
    __syncthreads();

    for (int kt = 0; kt < 32; ++kt) {
        const int cur = kt & 1;
        uint4 sA, sB;
        if (kt < 31) {                  // issue next tile's loads early
            if (isK) {
                size_t g = kbase + (size_t)((kt + 1) * 64 + sx) * 64 + sc8;
                sA = *(const uint4*)(Kh + g);
                sB = *(const uint4*)(Kl + g);
            } else {
                size_t g = kbase + (size_t)sx * 2048 + (kt + 1) * 64 + sc8;
                sA = *(const uint4*)(Vth + g);
                sB = *(const uint4*)(Vtl + g);
            }
        }

        u32 pm;
        MASK16(kt, pm);                 // thread-private threefry (pure VALU, 4-way ILP)

        f32x4v sfr[4];
        COMPUTE_S(sfr, kh_l[cur], kl_l[cur]);

#pragma unroll
        for (int n = 0; n < 4; ++n)
#pragma unroll
            for (int r = 0; r < 4; ++r) {
                float e = __expf(fmaf(sfr[n][r], 0.125f, -8.0f));
                float p = e * rsc[r];
                if (!((pm >> (n * 4 + r)) & 1u)) p = 0.0f;
                p_l[w][(kg * 4 + r) * LDK + n * 16 + lrow] = (f16)p;  // RTNE = astype(f16)
            }

        // PV: out += P(16f exact) * (Vh + Vl)   (wave-private p_l: no barrier)
#pragma unroll
        for (int ks = 0; ks < 2; ++ks) {
            f16x8 pa0 = *(const f16x8*)&p_l[w][lrow * LDK + ks * 32 + kg * 8];
#pragma unroll
            for (int fn = 0; fn < 4; ++fn) {
                const int voff = (fn * 16 + lrow) * LDK + ks * 32 + kg * 8;
                f16x8 vhf = *(const f16x8*)&vh_l[cur][voff];
                f16x8 vlf = *(const f16x8*)&vl_l[cur][voff];
                oacc[fn] = __builtin_amdgcn_mfma_f32_16x16x32_f16(pa0, vhf, oacc[fn], 0, 0, 0);
                oacc[fn] = __builtin_amdgcn_mfma_f32_16x16x32_f16(pa0, vlf, oacc[fn], 0, 0, 0);
            }
        }

        if (kt < 31) {                  // commit after compute
            if (isK) {
                *(uint4*)&kh_l[cur ^ 1][sx * LDK + sc8] = sA;
                *(uint4*)&kl_l[cur ^ 1][sx * LDK + sc8] = sB;
            } else {
                *(uint4*)&vh_l[cur ^ 1][sx * LDK + sc8] = sA;
                *(uint4*)&vl_l[cur ^ 1][sx * LDK + sc8] = sB;
            }
        }
        __syncthreads();                // single barrier per kt
    }

    // epilogue: out [b,h,s,e] fp32
#pragma unroll
    for (int fn = 0; fn < 4; ++fn)
#pragma unroll
        for (int r = 0; r < 4; ++r) {
            int row = qt * 256 + w * 16 + kg * 4 + r;
            out[((size_t)bh * 2048 + row) * 64 + fn * 16 + lrow] = oacc[fn][r];
        }
}

extern "C" void kernel_launch(void* const* d_in, const int* in_sizes, int n_in,
                              void* d_out, int out_size, void* d_ws, size_t ws_size,
                              hipStream_t stream) {
    (void)in_sizes; (void)n_in; (void)out_size; (void)ws_size;
    const float* query = (const float*)d_in[0];
    const float* key_  = (const float*)d_in[1];
    const float* value = (const float*)d_in[2];
    const float* Wq = (const float*)d_in[3];
    const float* bq = (const float*)d_in[4];
    const float* Wk = (const float*)d_in[5];
    const float* bk = (const float*)d_in[6];
    const float* Wv = (const float*)d_in[7];
    const float* bv = (const float*)d_in[8];

    char* ws = (char*)d_ws;                 // needs 48 MiB
    f16* Qh  = (f16*)(ws);
    f16* Ql  = (f16*)(ws + 8388608);
    f16* Kh  = (f16*)(ws + 16777216);
    f16* Kl  = (f16*)(ws + 25165824);
    f16* Vth = (f16*)(ws + 33554432);
    f16* Vtl = (f16*)(ws + 41943040);

    proj_qk_kernel<<<1024, 256, 0, stream>>>(query, key_, Wq, Wk, bq, bk, Qh, Ql, Kh, Kl);
    proj_v_kernel<<<dim3(16, 32), 256, 0, stream>>>(value, Wv, bv, Vth, Vtl);
    attn_kernel<<<dim3(8, 32), 1024, 0, stream>>>(Qh, Ql, Kh, Kl, Vth, Vtl, (float*)d_out);
}